// Round 3
// baseline (1798.772 us; speedup 1.0000x reference)
//
#include <hip/hip_runtime.h>
#include <math.h>

#define L_SEQ 4096
#define DM 256
#define DI 512

// ---------------- RMSNorm ----------------
// grid (8192 rows, 2 dirs), block 256 (= D_MODEL)
__global__ __launch_bounds__(256) void rmsnorm_kernel(
    const float* __restrict__ x,
    const float* __restrict__ w_fw, const float* __restrict__ w_bw,
    float* __restrict__ xn)
{
  int row = blockIdx.x;          // b*4096 + l
  int dir = blockIdx.y;
  int tid = threadIdx.x;
  const float* w = dir ? w_bw : w_fw;
  float v = x[row * DM + tid];
  float ss = v * v;
  #pragma unroll
  for (int m = 32; m; m >>= 1) ss += __shfl_xor(ss, m, 64);
  __shared__ float red[4];
  if ((tid & 63) == 0) red[tid >> 6] = ss;
  __syncthreads();
  float tot = red[0] + red[1] + red[2] + red[3];
  float sc = rsqrtf(tot / (float)DM + 1e-5f);
  xn[((size_t)dir * 8192 + row) * DM + tid] = v * sc * w[tid];
}

// ---------------- Generic GEMM: C[M,N] = A[M,K] * B[N,K]^T (+epilogue) ------
// epi: 0 = none, 1 = softplus(acc + ep_vec[n]), 2 = acc + ep_mat[m*ep_ld+n]
__global__ __launch_bounds__(256) void gemm_bt(
    const float* __restrict__ A, int lda,
    const float* __restrict__ B, int ldb,
    float* __restrict__ C, int ldc,
    int M, int N, int K,
    int epi, const float* __restrict__ ep_vec,
    const float* __restrict__ ep_mat, int ep_ld)
{
  __shared__ float As[16][64];
  __shared__ float Bs[16][64];
  int tid = threadIdx.x;
  int tx = tid & 15, ty = tid >> 4;
  int m0 = blockIdx.x * 64, n0 = blockIdx.y * 64;
  int lr = tid >> 2;          // 0..63 (row within tile)
  int lk = (tid & 3) << 2;    // 0,4,8,12 (k within tile)
  float acc[4][4] = {};

  for (int k0 = 0; k0 < K; k0 += 16) {
    float4 av = *(const float4*)&A[(size_t)(m0 + lr) * lda + k0 + lk];
    float4 bv = make_float4(0.f, 0.f, 0.f, 0.f);
    if (n0 + lr < N) bv = *(const float4*)&B[(size_t)(n0 + lr) * ldb + k0 + lk];
    __syncthreads();
    As[lk + 0][lr] = av.x; As[lk + 1][lr] = av.y;
    As[lk + 2][lr] = av.z; As[lk + 3][lr] = av.w;
    Bs[lk + 0][lr] = bv.x; Bs[lk + 1][lr] = bv.y;
    Bs[lk + 2][lr] = bv.z; Bs[lk + 3][lr] = bv.w;
    __syncthreads();
    #pragma unroll
    for (int kk = 0; kk < 16; kk++) {
      float4 a4 = *(const float4*)&As[kk][ty << 2];
      float4 b4 = *(const float4*)&Bs[kk][tx << 2];
      float ar[4] = {a4.x, a4.y, a4.z, a4.w};
      float br[4] = {b4.x, b4.y, b4.z, b4.w};
      #pragma unroll
      for (int i = 0; i < 4; i++)
        #pragma unroll
        for (int j = 0; j < 4; j++)
          acc[i][j] = fmaf(ar[i], br[j], acc[i][j]);
    }
  }

  #pragma unroll
  for (int i = 0; i < 4; i++) {
    int m = m0 + (ty << 2) + i;
    #pragma unroll
    for (int j = 0; j < 4; j++) {
      int n = n0 + (tx << 2) + j;
      if (n < N) {
        float v = acc[i][j];
        if (epi == 1) {
          v += ep_vec[n];
          v = fmaxf(v, 0.f) + log1pf(__expf(-fabsf(v)));  // stable softplus
        } else if (epi == 2) {
          v += ep_mat[(size_t)m * ep_ld + n];
        }
        C[(size_t)m * ldc + n] = v;
      }
    }
  }
}

// ---------------- Depthwise causal conv(4) + SiLU ----------------
// fw: xc[p,d] = silu(sum_j w[d,j]*xi[p-3+j] + b[d]); bw gathers p+3-j.
// grid (16384, 2), block 256
__global__ __launch_bounds__(256) void conv_silu_kernel(
    const float* __restrict__ xz,
    const float* __restrict__ cw_fw, const float* __restrict__ cb_fw,
    const float* __restrict__ cw_bw, const float* __restrict__ cb_bw,
    float* __restrict__ xc)
{
  int dir = blockIdx.y;
  int gid = blockIdx.x * 256 + threadIdx.x;  // over 8192*512
  int d = gid & 511;
  int row = gid >> 9;          // b*4096 + p
  int b = row >> 12, p = row & 4095;
  const float* cw = dir ? cw_bw : cw_fw;
  const float* cb = dir ? cb_bw : cb_fw;
  const float* xi = xz + (size_t)dir * 8192 * 1024;
  float acc = cb[d];
  #pragma unroll
  for (int j = 0; j < 4; j++) {
    int pp = dir ? (p + 3 - j) : (p - 3 + j);
    if (pp >= 0 && pp < 4096)
      acc = fmaf(cw[d * 4 + j], xi[((size_t)(b * 4096 + pp)) * 1024 + d], acc);
  }
  float s = acc / (1.f + __expf(-acc));
  xc[((size_t)dir * 8192 + row) * 512 + d] = s;
}

// ---------------- Selective scan ----------------
// grid (32 d-groups, 2 b, 2 dir), block 256 = 16 d x 16 n
__global__ __launch_bounds__(256) void scan_kernel(
    const float* __restrict__ xz, const float* __restrict__ xc,
    const float* __restrict__ dbl, const float* __restrict__ dtb,
    const float* __restrict__ Alog_fw, const float* __restrict__ Alog_bw,
    const float* __restrict__ Dp_fw, const float* __restrict__ Dp_bw,
    float* __restrict__ yv)
{
  int tid = threadIdx.x;
  int tx = tid & 15;     // n (state index)
  int ty = tid >> 4;     // d within group
  int dgrp = blockIdx.x; // 0..31
  int b = blockIdx.y, dir = blockIdx.z;
  int d = dgrp * 16 + ty;
  const float* Alog = dir ? Alog_bw : Alog_fw;
  const float* Dp   = dir ? Dp_bw : Dp_fw;
  float a  = -__expf(Alog[d * 16 + tx]);
  float Dd = Dp[d];
  int base = (dir * 2 + b) * 4096;
  int stepw = dir ? -1 : 1;
  int r = base + (dir ? 4095 : 0);

  // depth-1 prefetch
  float dtv = dtb[(size_t)r * 512 + d];
  float uv  = xc[(size_t)r * 512 + d];
  float Bv  = dbl[(size_t)r * 48 + 16 + tx];
  float Cv  = dbl[(size_t)r * 48 + 32 + tx];
  float zv  = xz[(size_t)r * 1024 + 512 + d];
  float h = 0.f;

  for (int t = 0; t < 4096; t++) {
    float dt_c = dtv, u_c = uv, B_c = Bv, C_c = Cv, z_c = zv;
    int rc = r;
    if (t < 4095) {
      r += stepw;
      dtv = dtb[(size_t)r * 512 + d];
      uv  = xc[(size_t)r * 512 + d];
      Bv  = dbl[(size_t)r * 48 + 16 + tx];
      Cv  = dbl[(size_t)r * 48 + 32 + tx];
      zv  = xz[(size_t)r * 1024 + 512 + d];
    }
    h = __expf(dt_c * a) * h + (dt_c * u_c) * B_c;
    float pq = h * C_c;
    #pragma unroll
    for (int m = 1; m < 16; m <<= 1) pq += __shfl_xor(pq, m, 16);
    if (tx == 0) {
      float sz = z_c / (1.f + __expf(-z_c));
      yv[(size_t)rc * 512 + d] = (pq + Dd * u_c) * sz;
    }
  }
}

extern "C" void kernel_launch(void* const* d_in, const int* in_sizes, int n_in,
                              void* d_out, int out_size, void* d_ws, size_t ws_size,
                              hipStream_t stream)
{
  const float* x = (const float*)d_in[0];
  const float* nw[2]     = {(const float*)d_in[1],  (const float*)d_in[11]};
  const float* inp[2]    = {(const float*)d_in[2],  (const float*)d_in[12]};
  const float* cw[2]     = {(const float*)d_in[3],  (const float*)d_in[13]};
  const float* cb[2]     = {(const float*)d_in[4],  (const float*)d_in[14]};
  const float* xp[2]     = {(const float*)d_in[5],  (const float*)d_in[15]};
  const float* dtw[2]    = {(const float*)d_in[6],  (const float*)d_in[16]};
  const float* dtbias[2] = {(const float*)d_in[7],  (const float*)d_in[17]};
  const float* alog[2]   = {(const float*)d_in[8],  (const float*)d_in[18]};
  const float* dvec[2]   = {(const float*)d_in[9],  (const float*)d_in[19]};
  const float* outp[2]   = {(const float*)d_in[10], (const float*)d_in[20]};

  float* ws  = (float*)d_ws;
  float* xn  = ws;                              // 2*8192*256   =  4.19M
  float* xz  = xn  + (size_t)2 * 8192 * 256;    // 2*8192*1024  = 16.78M
  float* xc  = xz  + (size_t)2 * 8192 * 1024;   // 2*8192*512   =  8.39M
  float* dbl = xc  + (size_t)2 * 8192 * 512;    // 2*8192*48    =  0.79M
  float* dtb = dbl + (size_t)2 * 8192 * 48;     // 2*8192*512   =  8.39M
  float* yv  = dtb + (size_t)2 * 8192 * 512;    // 2*8192*512   =  8.39M
  float* out = (float*)d_out;

  rmsnorm_kernel<<<dim3(8192, 2), 256, 0, stream>>>(x, nw[0], nw[1], xn);

  for (int dir = 0; dir < 2; dir++) {
    // in_proj: (8192x256) @ (1024x256)^T -> (8192x1024)
    gemm_bt<<<dim3(128, 16), 256, 0, stream>>>(
        xn + (size_t)dir * 8192 * 256, 256,
        inp[dir], 256,
        xz + (size_t)dir * 8192 * 1024, 1024,
        8192, 1024, 256, 0, nullptr, nullptr, 0);
  }

  conv_silu_kernel<<<dim3(16384, 2), 256, 0, stream>>>(
      xz, cw[0], cb[0], cw[1], cb[1], xc);

  for (int dir = 0; dir < 2; dir++) {
    // x_proj: (8192x512) @ (48x512)^T -> (8192x48)
    gemm_bt<<<dim3(128, 1), 256, 0, stream>>>(
        xc + (size_t)dir * 8192 * 512, 512,
        xp[dir], 512,
        dbl + (size_t)dir * 8192 * 48, 48,
        8192, 48, 512, 0, nullptr, nullptr, 0);
    // dt: (8192x16[lda48]) @ (512x16)^T -> softplus(+bias) -> (8192x512)
    gemm_bt<<<dim3(128, 8), 256, 0, stream>>>(
        dbl + (size_t)dir * 8192 * 48, 48,
        dtw[dir], 16,
        dtb + (size_t)dir * 8192 * 512, 512,
        8192, 512, 16, 1, dtbias[dir], nullptr, 0);
  }

  scan_kernel<<<dim3(32, 2, 2), 256, 0, stream>>>(
      xz, xc, dbl, dtb, alog[0], alog[1], dvec[0], dvec[1], yv);

  for (int dir = 0; dir < 2; dir++) {
    // out_proj: (8192x512) @ (256x512)^T + x -> out[..., dir*256:+256]
    gemm_bt<<<dim3(128, 4), 256, 0, stream>>>(
        yv + (size_t)dir * 8192 * 512, 512,
        outp[dir], 512,
        out + dir * 256, 512,
        8192, 256, 512, 2, nullptr, x, 256);
  }
}

// Round 4
// 580.830 us; speedup vs baseline: 3.0969x; 3.0969x over previous
//
#include <hip/hip_runtime.h>
#include <math.h>

#define L_SEQ 4096
#define DM 256
#define DI 512
#define NCHUNK 32
#define CLEN 128   // NCHUNK * CLEN == L_SEQ

// ---------------- RMSNorm ----------------
__global__ __launch_bounds__(256) void rmsnorm_kernel(
    const float* __restrict__ x,
    const float* __restrict__ w_fw, const float* __restrict__ w_bw,
    float* __restrict__ xn)
{
  int row = blockIdx.x;          // b*4096 + l
  int dir = blockIdx.y;
  int tid = threadIdx.x;
  const float* w = dir ? w_bw : w_fw;
  float v = x[row * DM + tid];
  float ss = v * v;
  #pragma unroll
  for (int m = 32; m; m >>= 1) ss += __shfl_xor(ss, m, 64);
  __shared__ float red[4];
  if ((tid & 63) == 0) red[tid >> 6] = ss;
  __syncthreads();
  float tot = red[0] + red[1] + red[2] + red[3];
  float sc = rsqrtf(tot / (float)DM + 1e-5f);
  xn[((size_t)dir * 8192 + row) * DM + tid] = v * sc * w[tid];
}

// ---------------- Generic GEMM: C[M,N] = A[M,K] * B[N,K]^T (+epilogue) ------
// epi: 0 = none, 1 = softplus(acc + ep_vec[n]), 2 = acc + ep_mat[m*ep_ld+n]
__global__ __launch_bounds__(256) void gemm_bt(
    const float* __restrict__ A, int lda,
    const float* __restrict__ B, int ldb,
    float* __restrict__ C, int ldc,
    int M, int N, int K,
    int epi, const float* __restrict__ ep_vec,
    const float* __restrict__ ep_mat, int ep_ld)
{
  __shared__ float As[16][64];
  __shared__ float Bs[16][64];
  int tid = threadIdx.x;
  int tx = tid & 15, ty = tid >> 4;
  int m0 = blockIdx.x * 64, n0 = blockIdx.y * 64;
  int lr = tid >> 2;          // 0..63 (row within tile)
  int lk = (tid & 3) << 2;    // 0,4,8,12 (k within tile)
  float acc[4][4] = {};

  for (int k0 = 0; k0 < K; k0 += 16) {
    float4 av = *(const float4*)&A[(size_t)(m0 + lr) * lda + k0 + lk];
    float4 bv = make_float4(0.f, 0.f, 0.f, 0.f);
    if (n0 + lr < N) bv = *(const float4*)&B[(size_t)(n0 + lr) * ldb + k0 + lk];
    __syncthreads();
    As[lk + 0][lr] = av.x; As[lk + 1][lr] = av.y;
    As[lk + 2][lr] = av.z; As[lk + 3][lr] = av.w;
    Bs[lk + 0][lr] = bv.x; Bs[lk + 1][lr] = bv.y;
    Bs[lk + 2][lr] = bv.z; Bs[lk + 3][lr] = bv.w;
    __syncthreads();
    #pragma unroll
    for (int kk = 0; kk < 16; kk++) {
      float4 a4 = *(const float4*)&As[kk][ty << 2];
      float4 b4 = *(const float4*)&Bs[kk][tx << 2];
      float ar[4] = {a4.x, a4.y, a4.z, a4.w};
      float br[4] = {b4.x, b4.y, b4.z, b4.w};
      #pragma unroll
      for (int i = 0; i < 4; i++)
        #pragma unroll
        for (int j = 0; j < 4; j++)
          acc[i][j] = fmaf(ar[i], br[j], acc[i][j]);
    }
  }

  #pragma unroll
  for (int i = 0; i < 4; i++) {
    int m = m0 + (ty << 2) + i;
    #pragma unroll
    for (int j = 0; j < 4; j++) {
      int n = n0 + (tx << 2) + j;
      if (n < N) {
        float v = acc[i][j];
        if (epi == 1) {
          v += ep_vec[n];
          v = fmaxf(v, 0.f) + log1pf(__expf(-fabsf(v)));  // stable softplus
        } else if (epi == 2) {
          v += ep_mat[(size_t)m * ep_ld + n];
        }
        C[(size_t)m * ldc + n] = v;
      }
    }
  }
}

// ---------------- Depthwise causal conv(4) + SiLU ----------------
__global__ __launch_bounds__(256) void conv_silu_kernel(
    const float* __restrict__ xz,
    const float* __restrict__ cw_fw, const float* __restrict__ cb_fw,
    const float* __restrict__ cw_bw, const float* __restrict__ cb_bw,
    float* __restrict__ xc)
{
  int dir = blockIdx.y;
  int gid = blockIdx.x * 256 + threadIdx.x;  // over 8192*512
  int d = gid & 511;
  int row = gid >> 9;          // b*4096 + p
  int b = row >> 12, p = row & 4095;
  const float* cw = dir ? cw_bw : cw_fw;
  const float* cb = dir ? cb_bw : cb_fw;
  const float* xi = xz + (size_t)dir * 8192 * 1024;
  float acc = cb[d];
  #pragma unroll
  for (int j = 0; j < 4; j++) {
    int pp = dir ? (p + 3 - j) : (p - 3 + j);
    if (pp >= 0 && pp < 4096)
      acc = fmaf(cw[d * 4 + j], xi[((size_t)(b * 4096 + pp)) * 1024 + d], acc);
  }
  float s = acc / (1.f + __expf(-acc));
  xc[((size_t)dir * 8192 + row) * 512 + d] = s;
}

// ---------------- Chunked selective scan ----------------
// h_{t+1} = exp(dt*a)*h_t + (dt*u)*B. Chunk composition is affine:
// h_out = exp(a*sum(dt)) * h_in + h_end(h_in=0).
// Phase 1: per-chunk (Ac, Bc).  grid (32 dgrp, NCHUNK, 4 bd), block 16d x 16n
__global__ __launch_bounds__(256) void scan_part1(
    const float* __restrict__ xc, const float* __restrict__ dbl,
    const float* __restrict__ dtb,
    const float* __restrict__ Alog_fw, const float* __restrict__ Alog_bw,
    float* __restrict__ Ac, float* __restrict__ Bc)
{
  int tid = threadIdx.x;
  int tx = tid & 15, ty = tid >> 4;
  int dgrp = blockIdx.x, c = blockIdx.y, bd = blockIdx.z;
  int dir = bd >> 1;
  int d = dgrp * 16 + ty;
  const float* Alog = dir ? Alog_bw : Alog_fw;
  float a = -__expf(Alog[d * 16 + tx]);

  int base = bd * 4096;
  int stepw = dir ? -1 : 1;
  int t0 = c * CLEN;
  int r = base + (dir ? 4095 - t0 : t0);

  float dtv = dtb[(size_t)r * 512 + d];
  float uv  = xc[(size_t)r * 512 + d];
  float Bv  = dbl[(size_t)r * 48 + 16 + tx];
  float h = 0.f, sdt = 0.f;

  for (int i = 0; i < CLEN; i++) {
    float dt_c = dtv, u_c = uv, B_c = Bv;
    if (i < CLEN - 1) {
      r += stepw;
      dtv = dtb[(size_t)r * 512 + d];
      uv  = xc[(size_t)r * 512 + d];
      Bv  = dbl[(size_t)r * 48 + 16 + tx];
    }
    sdt += dt_c;
    h = __expf(dt_c * a) * h + (dt_c * u_c) * B_c;
  }
  size_t idx = ((size_t)bd * NCHUNK + c) * 8192 + d * 16 + tx;
  Ac[idx] = __expf(a * sdt);
  Bc[idx] = h;
}

// Phase 2: sequential over chunks, parallel over 4*8192 lanes.
// grid 128, block 256
__global__ __launch_bounds__(256) void scan_mid(
    const float* __restrict__ Ac, const float* __restrict__ Bc,
    float* __restrict__ Hin)
{
  int gid = blockIdx.x * 256 + threadIdx.x;   // 0..32767
  int bd = gid >> 13, pos = gid & 8191;
  float h = 0.f;
  for (int c = 0; c < NCHUNK; c++) {
    size_t idx = ((size_t)bd * NCHUNK + c) * 8192 + pos;
    Hin[idx] = h;
    h = Ac[idx] * h + Bc[idx];
  }
}

// Phase 3: exact local rescan from Hin, emit y. Same grid as phase 1.
__global__ __launch_bounds__(256) void scan_part2(
    const float* __restrict__ xz, const float* __restrict__ xc,
    const float* __restrict__ dbl, const float* __restrict__ dtb,
    const float* __restrict__ Alog_fw, const float* __restrict__ Alog_bw,
    const float* __restrict__ Dp_fw, const float* __restrict__ Dp_bw,
    const float* __restrict__ Hin, float* __restrict__ yv)
{
  int tid = threadIdx.x;
  int tx = tid & 15, ty = tid >> 4;
  int dgrp = blockIdx.x, c = blockIdx.y, bd = blockIdx.z;
  int dir = bd >> 1;
  int d = dgrp * 16 + ty;
  const float* Alog = dir ? Alog_bw : Alog_fw;
  const float* Dp   = dir ? Dp_bw : Dp_fw;
  float a  = -__expf(Alog[d * 16 + tx]);
  float Dd = Dp[d];

  int base = bd * 4096;
  int stepw = dir ? -1 : 1;
  int t0 = c * CLEN;
  int r = base + (dir ? 4095 - t0 : t0);

  float h = Hin[((size_t)bd * NCHUNK + c) * 8192 + d * 16 + tx];

  float dtv = dtb[(size_t)r * 512 + d];
  float uv  = xc[(size_t)r * 512 + d];
  float Bv  = dbl[(size_t)r * 48 + 16 + tx];
  float Cv  = dbl[(size_t)r * 48 + 32 + tx];
  float zv  = xz[(size_t)r * 1024 + 512 + d];

  for (int i = 0; i < CLEN; i++) {
    float dt_c = dtv, u_c = uv, B_c = Bv, C_c = Cv, z_c = zv;
    int rc = r;
    if (i < CLEN - 1) {
      r += stepw;
      dtv = dtb[(size_t)r * 512 + d];
      uv  = xc[(size_t)r * 512 + d];
      Bv  = dbl[(size_t)r * 48 + 16 + tx];
      Cv  = dbl[(size_t)r * 48 + 32 + tx];
      zv  = xz[(size_t)r * 1024 + 512 + d];
    }
    h = __expf(dt_c * a) * h + (dt_c * u_c) * B_c;
    float pq = h * C_c;
    #pragma unroll
    for (int m = 1; m < 16; m <<= 1) pq += __shfl_xor(pq, m, 16);
    if (tx == 0) {
      float sz = z_c / (1.f + __expf(-z_c));
      yv[(size_t)rc * 512 + d] = (pq + Dd * u_c) * sz;
    }
  }
}

extern "C" void kernel_launch(void* const* d_in, const int* in_sizes, int n_in,
                              void* d_out, int out_size, void* d_ws, size_t ws_size,
                              hipStream_t stream)
{
  const float* x = (const float*)d_in[0];
  const float* nw[2]     = {(const float*)d_in[1],  (const float*)d_in[11]};
  const float* inp[2]    = {(const float*)d_in[2],  (const float*)d_in[12]};
  const float* cw[2]     = {(const float*)d_in[3],  (const float*)d_in[13]};
  const float* cb[2]     = {(const float*)d_in[4],  (const float*)d_in[14]};
  const float* xp[2]     = {(const float*)d_in[5],  (const float*)d_in[15]};
  const float* dtw[2]    = {(const float*)d_in[6],  (const float*)d_in[16]};
  const float* dtbias[2] = {(const float*)d_in[7],  (const float*)d_in[17]};
  const float* alog[2]   = {(const float*)d_in[8],  (const float*)d_in[18]};
  const float* dvec[2]   = {(const float*)d_in[9],  (const float*)d_in[19]};
  const float* outp[2]   = {(const float*)d_in[10], (const float*)d_in[20]};

  float* ws  = (float*)d_ws;
  float* xn  = ws;                              // 2*8192*256   =  4.19M floats
  float* xz  = xn  + (size_t)2 * 8192 * 256;    // 2*8192*1024  = 16.78M
  float* xc  = xz  + (size_t)2 * 8192 * 1024;   // 2*8192*512   =  8.39M
  float* dbl = xc  + (size_t)2 * 8192 * 512;    // 2*8192*48    =  0.79M
  float* dtb = dbl + (size_t)2 * 8192 * 48;     // 2*8192*512   =  8.39M
  float* yv  = dtb + (size_t)2 * 8192 * 512;    // 2*8192*512   =  8.39M
  // Ac/Bc/Hin (3 x 4*NCHUNK*8192 = 3.15M floats) reuse the xn region:
  // xn is dead after the in_proj GEMMs, scan runs strictly later.
  float* Ac  = xn;                              // 1.05M floats
  float* Bc  = Ac + (size_t)4 * NCHUNK * 8192;
  float* Hin = Bc + (size_t)4 * NCHUNK * 8192;
  float* out = (float*)d_out;

  rmsnorm_kernel<<<dim3(8192, 2), 256, 0, stream>>>(x, nw[0], nw[1], xn);

  for (int dir = 0; dir < 2; dir++) {
    // in_proj: (8192x256) @ (1024x256)^T -> (8192x1024)
    gemm_bt<<<dim3(128, 16), 256, 0, stream>>>(
        xn + (size_t)dir * 8192 * 256, 256,
        inp[dir], 256,
        xz + (size_t)dir * 8192 * 1024, 1024,
        8192, 1024, 256, 0, nullptr, nullptr, 0);
  }

  conv_silu_kernel<<<dim3(16384, 2), 256, 0, stream>>>(
      xz, cw[0], cb[0], cw[1], cb[1], xc);

  for (int dir = 0; dir < 2; dir++) {
    // x_proj: (8192x512) @ (48x512)^T -> (8192x48)
    gemm_bt<<<dim3(128, 1), 256, 0, stream>>>(
        xc + (size_t)dir * 8192 * 512, 512,
        xp[dir], 512,
        dbl + (size_t)dir * 8192 * 48, 48,
        8192, 48, 512, 0, nullptr, nullptr, 0);
    // dt: (8192x16[lda48]) @ (512x16)^T -> softplus(+bias) -> (8192x512)
    gemm_bt<<<dim3(128, 8), 256, 0, stream>>>(
        dbl + (size_t)dir * 8192 * 48, 48,
        dtw[dir], 16,
        dtb + (size_t)dir * 8192 * 512, 512,
        8192, 512, 16, 1, dtbias[dir], nullptr, 0);
  }

  scan_part1<<<dim3(32, NCHUNK, 4), 256, 0, stream>>>(
      xc, dbl, dtb, alog[0], alog[1], Ac, Bc);
  scan_mid<<<dim3(128), 256, 0, stream>>>(Ac, Bc, Hin);
  scan_part2<<<dim3(32, NCHUNK, 4), 256, 0, stream>>>(
      xz, xc, dbl, dtb, alog[0], alog[1], dvec[0], dvec[1], Hin, yv);

  for (int dir = 0; dir < 2; dir++) {
    // out_proj: (8192x512) @ (256x512)^T + x -> out[..., dir*256:+256]
    gemm_bt<<<dim3(128, 4), 256, 0, stream>>>(
        yv + (size_t)dir * 8192 * 512, 512,
        outp[dir], 512,
        out + dir * 256, 512,
        8192, 256, 512, 2, nullptr, x, 256);
  }
}

// Round 5
// 464.960 us; speedup vs baseline: 3.8687x; 1.2492x over previous
//
#include <hip/hip_runtime.h>
#include <math.h>

#define L_SEQ 4096
#define DM 256
#define DI 512
#define NCHUNK 64
#define CLEN 64   // NCHUNK * CLEN == L_SEQ

// ---------------- RMSNorm ----------------
__global__ __launch_bounds__(256) void rmsnorm_kernel(
    const float* __restrict__ x,
    const float* __restrict__ w_fw, const float* __restrict__ w_bw,
    float* __restrict__ xn)
{
  int row = blockIdx.x;          // b*4096 + l
  int dir = blockIdx.y;
  int tid = threadIdx.x;
  const float* w = dir ? w_bw : w_fw;
  float v = x[row * DM + tid];
  float ss = v * v;
  #pragma unroll
  for (int m = 32; m; m >>= 1) ss += __shfl_xor(ss, m, 64);
  __shared__ float red[4];
  if ((tid & 63) == 0) red[tid >> 6] = ss;
  __syncthreads();
  float tot = red[0] + red[1] + red[2] + red[3];
  float sc = rsqrtf(tot / (float)DM + 1e-5f);
  xn[((size_t)dir * 8192 + row) * DM + tid] = v * sc * w[tid];
}

// ---------------- Generic GEMM: C[M,N] = A[M,K] * B[N,K]^T (+epilogue) ------
// epi: 0 = none, 1 = softplus(acc + ep_vec[n]), 2 = acc + ep_mat[m*ep_ld+n]
__global__ __launch_bounds__(256) void gemm_bt(
    const float* __restrict__ A, int lda,
    const float* __restrict__ B, int ldb,
    float* __restrict__ C, int ldc,
    int M, int N, int K,
    int epi, const float* __restrict__ ep_vec,
    const float* __restrict__ ep_mat, int ep_ld)
{
  __shared__ float As[16][64];
  __shared__ float Bs[16][64];
  int tid = threadIdx.x;
  int tx = tid & 15, ty = tid >> 4;
  int m0 = blockIdx.x * 64, n0 = blockIdx.y * 64;
  int lr = tid >> 2;          // 0..63 (row within tile)
  int lk = (tid & 3) << 2;    // 0,4,8,12 (k within tile)
  float acc[4][4] = {};

  for (int k0 = 0; k0 < K; k0 += 16) {
    float4 av = *(const float4*)&A[(size_t)(m0 + lr) * lda + k0 + lk];
    float4 bv = make_float4(0.f, 0.f, 0.f, 0.f);
    if (n0 + lr < N) bv = *(const float4*)&B[(size_t)(n0 + lr) * ldb + k0 + lk];
    __syncthreads();
    As[lk + 0][lr] = av.x; As[lk + 1][lr] = av.y;
    As[lk + 2][lr] = av.z; As[lk + 3][lr] = av.w;
    Bs[lk + 0][lr] = bv.x; Bs[lk + 1][lr] = bv.y;
    Bs[lk + 2][lr] = bv.z; Bs[lk + 3][lr] = bv.w;
    __syncthreads();
    #pragma unroll
    for (int kk = 0; kk < 16; kk++) {
      float4 a4 = *(const float4*)&As[kk][ty << 2];
      float4 b4 = *(const float4*)&Bs[kk][tx << 2];
      float ar[4] = {a4.x, a4.y, a4.z, a4.w};
      float br[4] = {b4.x, b4.y, b4.z, b4.w};
      #pragma unroll
      for (int i = 0; i < 4; i++)
        #pragma unroll
        for (int j = 0; j < 4; j++)
          acc[i][j] = fmaf(ar[i], br[j], acc[i][j]);
    }
  }

  #pragma unroll
  for (int i = 0; i < 4; i++) {
    int m = m0 + (ty << 2) + i;
    #pragma unroll
    for (int j = 0; j < 4; j++) {
      int n = n0 + (tx << 2) + j;
      if (n < N) {
        float v = acc[i][j];
        if (epi == 1) {
          v += ep_vec[n];
          v = fmaxf(v, 0.f) + log1pf(__expf(-fabsf(v)));  // stable softplus
        } else if (epi == 2) {
          v += ep_mat[(size_t)m * ep_ld + n];
        }
        C[(size_t)m * ldc + n] = v;
      }
    }
  }
}

// ---------------- Depthwise causal conv(4) + SiLU ----------------
__global__ __launch_bounds__(256) void conv_silu_kernel(
    const float* __restrict__ xz,
    const float* __restrict__ cw_fw, const float* __restrict__ cb_fw,
    const float* __restrict__ cw_bw, const float* __restrict__ cb_bw,
    float* __restrict__ xc)
{
  int dir = blockIdx.y;
  int gid = blockIdx.x * 256 + threadIdx.x;  // over 8192*512
  int d = gid & 511;
  int row = gid >> 9;          // b*4096 + p
  int b = row >> 12, p = row & 4095;
  const float* cw = dir ? cw_bw : cw_fw;
  const float* cb = dir ? cb_bw : cb_fw;
  const float* xi = xz + (size_t)dir * 8192 * 1024;
  float acc = cb[d];
  #pragma unroll
  for (int j = 0; j < 4; j++) {
    int pp = dir ? (p + 3 - j) : (p - 3 + j);
    if (pp >= 0 && pp < 4096)
      acc = fmaf(cw[d * 4 + j], xi[((size_t)(b * 4096 + pp)) * 1024 + d], acc);
  }
  float s = acc / (1.f + __expf(-acc));
  xc[((size_t)dir * 8192 + row) * 512 + d] = s;
}

// ---------------- Chunked selective scan, h-per-thread layout ----------------
// Thread owns one d and ALL 16 n-states in registers; y-reduction is local.
// B/C rows are workgroup-uniform -> scalar loads.
// Phase 1: per-chunk (Ac, Bc). grid (2 dblk, NCHUNK, 4 bd), block 256
__global__ __launch_bounds__(256) void scan_part1(
    const float* __restrict__ xc, const float* __restrict__ dbl,
    const float* __restrict__ dtb,
    const float* __restrict__ Alog_fw, const float* __restrict__ Alog_bw,
    float* __restrict__ Ac, float* __restrict__ Bc)
{
  int tid = threadIdx.x;
  int d = blockIdx.x * 256 + tid;
  int c = blockIdx.y, bd = blockIdx.z, dir = bd >> 1;
  const float* Alog = dir ? Alog_bw : Alog_fw;

  float a[16], h[16];
  #pragma unroll
  for (int n = 0; n < 16; n++) { a[n] = -__expf(Alog[d * 16 + n]); h[n] = 0.f; }

  int base = bd * 4096;
  int stepw = dir ? -1 : 1;
  int t0 = c * CLEN;
  int r = base + (dir ? 4095 - t0 : t0);

  float dtv = dtb[(size_t)r * 512 + d];
  float uv  = xc[(size_t)r * 512 + d];
  float Bn[16];
  {
    const float* br = dbl + (size_t)r * 48 + 16;
    #pragma unroll
    for (int n = 0; n < 16; n++) Bn[n] = br[n];
  }
  float sdt = 0.f;

  for (int i = 0; i < CLEN; i++) {
    float dt_c = dtv, u_c = uv;
    float Bl[16];
    #pragma unroll
    for (int n = 0; n < 16; n++) Bl[n] = Bn[n];
    if (i < CLEN - 1) {
      r += stepw;
      dtv = dtb[(size_t)r * 512 + d];
      uv  = xc[(size_t)r * 512 + d];
      const float* br = dbl + (size_t)r * 48 + 16;
      #pragma unroll
      for (int n = 0; n < 16; n++) Bn[n] = br[n];
    }
    sdt += dt_c;
    float dtu = dt_c * u_c;
    #pragma unroll
    for (int n = 0; n < 16; n++) {
      float g = __expf(dt_c * a[n]);
      h[n] = fmaf(g, h[n], dtu * Bl[n]);
    }
  }
  size_t ob = (((size_t)bd * NCHUNK + c) * 512 + d) * 16;
  #pragma unroll
  for (int n = 0; n < 16; n++) {
    Ac[ob + n] = __expf(a[n] * sdt);
    Bc[ob + n] = h[n];
  }
}

// Phase 2: sequential over chunks, parallel over 4*8192 (bd, d*16+n) lanes.
// grid 128, block 256
__global__ __launch_bounds__(256) void scan_mid(
    const float* __restrict__ Ac, const float* __restrict__ Bc,
    float* __restrict__ Hin)
{
  int gid = blockIdx.x * 256 + threadIdx.x;   // 0..32767
  int bd = gid >> 13, pos = gid & 8191;
  float h = 0.f;
  for (int c = 0; c < NCHUNK; c++) {
    size_t idx = ((size_t)bd * NCHUNK + c) * 8192 + pos;
    Hin[idx] = h;
    h = Ac[idx] * h + Bc[idx];
  }
}

// Phase 3: exact local rescan from Hin, emit y. grid (2, NCHUNK, 4), block 256
__global__ __launch_bounds__(256) void scan_part2(
    const float* __restrict__ xz, const float* __restrict__ xc,
    const float* __restrict__ dbl, const float* __restrict__ dtb,
    const float* __restrict__ Alog_fw, const float* __restrict__ Alog_bw,
    const float* __restrict__ Dp_fw, const float* __restrict__ Dp_bw,
    const float* __restrict__ Hin, float* __restrict__ yv)
{
  int tid = threadIdx.x;
  int d = blockIdx.x * 256 + tid;
  int c = blockIdx.y, bd = blockIdx.z, dir = bd >> 1;
  const float* Alog = dir ? Alog_bw : Alog_fw;
  const float* Dp   = dir ? Dp_bw : Dp_fw;
  float Dd = Dp[d];

  float a[16], h[16];
  size_t ob = (((size_t)bd * NCHUNK + c) * 512 + d) * 16;
  #pragma unroll
  for (int n = 0; n < 16; n++) {
    a[n] = -__expf(Alog[d * 16 + n]);
    h[n] = Hin[ob + n];
  }

  int base = bd * 4096;
  int stepw = dir ? -1 : 1;
  int t0 = c * CLEN;
  int r = base + (dir ? 4095 - t0 : t0);

  float dtv = dtb[(size_t)r * 512 + d];
  float uv  = xc[(size_t)r * 512 + d];
  float zv  = xz[(size_t)r * 1024 + 512 + d];
  float Bn[16], Cn[16];
  {
    const float* br = dbl + (size_t)r * 48 + 16;
    #pragma unroll
    for (int n = 0; n < 16; n++) { Bn[n] = br[n]; Cn[n] = br[16 + n]; }
  }

  for (int i = 0; i < CLEN; i++) {
    float dt_c = dtv, u_c = uv, z_c = zv;
    int rc = r;
    float Bl[16], Cl[16];
    #pragma unroll
    for (int n = 0; n < 16; n++) { Bl[n] = Bn[n]; Cl[n] = Cn[n]; }
    if (i < CLEN - 1) {
      r += stepw;
      dtv = dtb[(size_t)r * 512 + d];
      uv  = xc[(size_t)r * 512 + d];
      zv  = xz[(size_t)r * 1024 + 512 + d];
      const float* br = dbl + (size_t)r * 48 + 16;
      #pragma unroll
      for (int n = 0; n < 16; n++) { Bn[n] = br[n]; Cn[n] = br[16 + n]; }
    }
    float dtu = dt_c * u_c;
    float y = 0.f;
    #pragma unroll
    for (int n = 0; n < 16; n++) {
      float g = __expf(dt_c * a[n]);
      h[n] = fmaf(g, h[n], dtu * Bl[n]);
      y = fmaf(h[n], Cl[n], y);
    }
    float sz = z_c / (1.f + __expf(-z_c));
    yv[(size_t)rc * 512 + d] = (y + Dd * u_c) * sz;
  }
}

extern "C" void kernel_launch(void* const* d_in, const int* in_sizes, int n_in,
                              void* d_out, int out_size, void* d_ws, size_t ws_size,
                              hipStream_t stream)
{
  const float* x = (const float*)d_in[0];
  const float* nw[2]     = {(const float*)d_in[1],  (const float*)d_in[11]};
  const float* inp[2]    = {(const float*)d_in[2],  (const float*)d_in[12]};
  const float* cw[2]     = {(const float*)d_in[3],  (const float*)d_in[13]};
  const float* cb[2]     = {(const float*)d_in[4],  (const float*)d_in[14]};
  const float* xp[2]     = {(const float*)d_in[5],  (const float*)d_in[15]};
  const float* dtw[2]    = {(const float*)d_in[6],  (const float*)d_in[16]};
  const float* dtbias[2] = {(const float*)d_in[7],  (const float*)d_in[17]};
  const float* alog[2]   = {(const float*)d_in[8],  (const float*)d_in[18]};
  const float* dvec[2]   = {(const float*)d_in[9],  (const float*)d_in[19]};
  const float* outp[2]   = {(const float*)d_in[10], (const float*)d_in[20]};

  float* ws  = (float*)d_ws;
  float* xn  = ws;                              // 2*8192*256   =  4.19M floats
  float* xz  = xn  + (size_t)2 * 8192 * 256;    // 2*8192*1024  = 16.78M
  float* xc  = xz  + (size_t)2 * 8192 * 1024;   // 2*8192*512   =  8.39M
  float* dbl = xc  + (size_t)2 * 8192 * 512;    // 2*8192*48    =  0.79M
  float* dtb = dbl + (size_t)2 * 8192 * 48;     // 2*8192*512   =  8.39M
  float* yv  = dtb + (size_t)2 * 8192 * 512;    // 2*8192*512   =  8.39M
  // Ac+Bc (2 x 4*NCHUNK*8192 = 4.19M floats) exactly fill the dead xn region.
  // Hin (2.10M floats) lives in d_out, which the final out_proj fully rewrites.
  float* Ac  = xn;
  float* Bc  = Ac + (size_t)4 * NCHUNK * 8192;
  float* Hin = (float*)d_out;
  float* out = (float*)d_out;

  rmsnorm_kernel<<<dim3(8192, 2), 256, 0, stream>>>(x, nw[0], nw[1], xn);

  for (int dir = 0; dir < 2; dir++) {
    // in_proj: (8192x256) @ (1024x256)^T -> (8192x1024)
    gemm_bt<<<dim3(128, 16), 256, 0, stream>>>(
        xn + (size_t)dir * 8192 * 256, 256,
        inp[dir], 256,
        xz + (size_t)dir * 8192 * 1024, 1024,
        8192, 1024, 256, 0, nullptr, nullptr, 0);
  }

  conv_silu_kernel<<<dim3(16384, 2), 256, 0, stream>>>(
      xz, cw[0], cb[0], cw[1], cb[1], xc);

  for (int dir = 0; dir < 2; dir++) {
    // x_proj: (8192x512) @ (48x512)^T -> (8192x48)
    gemm_bt<<<dim3(128, 1), 256, 0, stream>>>(
        xc + (size_t)dir * 8192 * 512, 512,
        xp[dir], 512,
        dbl + (size_t)dir * 8192 * 48, 48,
        8192, 48, 512, 0, nullptr, nullptr, 0);
    // dt: (8192x16[lda48]) @ (512x16)^T -> softplus(+bias) -> (8192x512)
    gemm_bt<<<dim3(128, 8), 256, 0, stream>>>(
        dbl + (size_t)dir * 8192 * 48, 48,
        dtw[dir], 16,
        dtb + (size_t)dir * 8192 * 512, 512,
        8192, 512, 16, 1, dtbias[dir], nullptr, 0);
  }

  scan_part1<<<dim3(2, NCHUNK, 4), 256, 0, stream>>>(
      xc, dbl, dtb, alog[0], alog[1], Ac, Bc);
  scan_mid<<<dim3(128), 256, 0, stream>>>(Ac, Bc, Hin);
  scan_part2<<<dim3(2, NCHUNK, 4), 256, 0, stream>>>(
      xz, xc, dbl, dtb, alog[0], alog[1], dvec[0], dvec[1], Hin, yv);

  for (int dir = 0; dir < 2; dir++) {
    // out_proj: (8192x512) @ (256x512)^T + x -> out[..., dir*256:+256]
    gemm_bt<<<dim3(128, 4), 256, 0, stream>>>(
        yv + (size_t)dir * 8192 * 512, 512,
        outp[dir], 512,
        out + dir * 256, 512,
        8192, 256, 512, 2, nullptr, x, 256);
  }
}

// Round 6
// 300.371 us; speedup vs baseline: 5.9885x; 1.5479x over previous
//
#include <hip/hip_runtime.h>
#include <hip/hip_bf16.h>
#include <math.h>

#define NCHUNK 64
#define CLEN 64   // NCHUNK * CLEN == 4096

typedef __attribute__((ext_vector_type(8))) short short8;
typedef __attribute__((ext_vector_type(4))) float f32x4;

__device__ __forceinline__ void gload16(const void* g, void* l) {
  __builtin_amdgcn_global_load_lds(
      (const __attribute__((address_space(1))) void*)g,
      (__attribute__((address_space(3))) void*)l, 16, 0, 0);
}

// ---------------- weight cast: 6 fp32 tensors -> one contiguous bf16 buffer --
// layout: fw_in[262144] bw_in[262144] fw_out[131072] bw_out[131072]
//         fw_xp[24576] bw_xp[24576]   total 835584
__global__ __launch_bounds__(256) void cast_weights(
    const float* __restrict__ a0, const float* __restrict__ a1,
    const float* __restrict__ a2, const float* __restrict__ a3,
    const float* __restrict__ a4, const float* __restrict__ a5,
    __hip_bfloat16* __restrict__ dst)
{
  int gid = blockIdx.x * 256 + threadIdx.x;
  if (gid >= 835584) return;
  int off = gid; const float* s;
  if (off < 262144) s = a0;
  else if ((off -= 262144) < 262144) s = a1;
  else if ((off -= 262144) < 131072) s = a2;
  else if ((off -= 131072) < 131072) s = a3;
  else if ((off -= 131072) < 24576) s = a4;
  else { off -= 24576; s = a5; }
  dst[gid] = __float2bfloat16(s[off]);
}

// ---------------- RMSNorm (bf16 output) ----------------
__global__ __launch_bounds__(256) void rmsnorm_kernel(
    const float* __restrict__ x,
    const float* __restrict__ w_fw, const float* __restrict__ w_bw,
    __hip_bfloat16* __restrict__ xnh)
{
  int row = blockIdx.x;          // b*4096 + l
  int dir = blockIdx.y;
  int tid = threadIdx.x;
  const float* w = dir ? w_bw : w_fw;
  float v = x[row * 256 + tid];
  float ss = v * v;
  #pragma unroll
  for (int m = 32; m; m >>= 1) ss += __shfl_xor(ss, m, 64);
  __shared__ float red[4];
  if ((tid & 63) == 0) red[tid >> 6] = ss;
  __syncthreads();
  float tot = red[0] + red[1] + red[2] + red[3];
  float sc = rsqrtf(tot / 256.f + 1e-5f);
  xnh[((size_t)dir * 8192 + row) * 256 + tid] = __float2bfloat16(v * sc * w[tid]);
}

// ---------------- bf16 MFMA GEMM: C[M,N] = A[M,K] * B[N,K]^T ----------------
// 128x128 tile, BK=32, 256 threads (4 waves, 2x2 wave grid of 64x64).
// M%128==0, K%32==0 required; N guarded (B row clamp + store guard).
// epi: 0 none, 2: + ep_mat[m*ep_ld+n]
__global__ __launch_bounds__(256) void gemm_mfma(
    const __hip_bfloat16* __restrict__ A, int lda,
    const __hip_bfloat16* __restrict__ B, int ldb,
    float* __restrict__ C, int ldc,
    int M, int N, int K,
    int epi, const float* __restrict__ ep_mat, int ep_ld)
{
  __shared__ __align__(16) __hip_bfloat16 As[128 * 32];
  __shared__ __align__(16) __hip_bfloat16 Bs[128 * 32];
  int tid = threadIdx.x;
  int lane = tid & 63, wid = tid >> 6;
  int m0 = blockIdx.x * 128, n0 = blockIdx.y * 128;
  int wr = wid & 1, wc = wid >> 1;   // wave computes rows wr*64.., cols wc*64..

  f32x4 acc[4][4] = {};

  int lrow = lane >> 2;        // row within 16-row staging region
  int lk8  = (lane & 3) * 8;   // bf16 element offset (16B granules)

  for (int k0 = 0; k0 < K; k0 += 32) {
    __syncthreads();           // previous iteration's ds_reads complete
    #pragma unroll
    for (int s = 0; s < 2; s++) {
      int r = wid * 2 + s;     // staging region 0..7 (uniform per wave)
      int arow = m0 + r * 16 + lrow;
      gload16(A + (size_t)arow * lda + k0 + lk8, &As[r * 512]);
      int brow = n0 + r * 16 + lrow;
      if (brow > N - 1) brow = N - 1;
      gload16(B + (size_t)brow * ldb + k0 + lk8, &Bs[r * 512]);
    }
    __syncthreads();           // drains vmcnt -> LDS tiles ready

    short8 af[4], bfr[4];
    #pragma unroll
    for (int i = 0; i < 4; i++)
      af[i] = *(const short8*)&As[(wr * 64 + i * 16 + (lane & 15)) * 32 + (lane >> 4) * 8];
    #pragma unroll
    for (int j = 0; j < 4; j++)
      bfr[j] = *(const short8*)&Bs[(wc * 64 + j * 16 + (lane & 15)) * 32 + (lane >> 4) * 8];
    #pragma unroll
    for (int i = 0; i < 4; i++)
      #pragma unroll
      for (int j = 0; j < 4; j++)
        acc[i][j] = __builtin_amdgcn_mfma_f32_16x16x32_bf16(af[i], bfr[j], acc[i][j], 0, 0, 0);
  }

  int crow = (lane >> 4) * 4;
  int ccol = lane & 15;
  #pragma unroll
  for (int i = 0; i < 4; i++) {
    #pragma unroll
    for (int j = 0; j < 4; j++) {
      int nn = n0 + wc * 64 + j * 16 + ccol;
      if (nn < N) {
        #pragma unroll
        for (int q = 0; q < 4; q++) {
          int mm = m0 + wr * 64 + i * 16 + crow + q;
          float v = acc[i][j][q];
          if (epi == 2) v += ep_mat[(size_t)mm * ep_ld + nn];
          C[(size_t)mm * ldc + nn] = v;
        }
      }
    }
  }
}

// ---------------- fp32 GEMM (kept for dt: K=16) ----------------
// epi: 1 = softplus(acc + ep_vec[n])
__global__ __launch_bounds__(256) void gemm_bt(
    const float* __restrict__ A, int lda,
    const float* __restrict__ B, int ldb,
    float* __restrict__ C, int ldc,
    int M, int N, int K,
    int epi, const float* __restrict__ ep_vec,
    const float* __restrict__ ep_mat, int ep_ld)
{
  __shared__ float As[16][64];
  __shared__ float Bs[16][64];
  int tid = threadIdx.x;
  int tx = tid & 15, ty = tid >> 4;
  int m0 = blockIdx.x * 64, n0 = blockIdx.y * 64;
  int lr = tid >> 2;
  int lk = (tid & 3) << 2;
  float acc[4][4] = {};

  for (int k0 = 0; k0 < K; k0 += 16) {
    float4 av = *(const float4*)&A[(size_t)(m0 + lr) * lda + k0 + lk];
    float4 bv = make_float4(0.f, 0.f, 0.f, 0.f);
    if (n0 + lr < N) bv = *(const float4*)&B[(size_t)(n0 + lr) * ldb + k0 + lk];
    __syncthreads();
    As[lk + 0][lr] = av.x; As[lk + 1][lr] = av.y;
    As[lk + 2][lr] = av.z; As[lk + 3][lr] = av.w;
    Bs[lk + 0][lr] = bv.x; Bs[lk + 1][lr] = bv.y;
    Bs[lk + 2][lr] = bv.z; Bs[lk + 3][lr] = bv.w;
    __syncthreads();
    #pragma unroll
    for (int kk = 0; kk < 16; kk++) {
      float4 a4 = *(const float4*)&As[kk][ty << 2];
      float4 b4 = *(const float4*)&Bs[kk][tx << 2];
      float ar[4] = {a4.x, a4.y, a4.z, a4.w};
      float br[4] = {b4.x, b4.y, b4.z, b4.w};
      #pragma unroll
      for (int i = 0; i < 4; i++)
        #pragma unroll
        for (int j = 0; j < 4; j++)
          acc[i][j] = fmaf(ar[i], br[j], acc[i][j]);
    }
  }

  #pragma unroll
  for (int i = 0; i < 4; i++) {
    int m = m0 + (ty << 2) + i;
    #pragma unroll
    for (int j = 0; j < 4; j++) {
      int n = n0 + (tx << 2) + j;
      if (n < N) {
        float v = acc[i][j];
        if (epi == 1) {
          v += ep_vec[n];
          v = fmaxf(v, 0.f) + log1pf(__expf(-fabsf(v)));
        } else if (epi == 2) {
          v += ep_mat[(size_t)m * ep_ld + n];
        }
        C[(size_t)m * ldc + n] = v;
      }
    }
  }
}

// ---------------- Depthwise causal conv(4) + SiLU (f32 + bf16 outputs) ------
__global__ __launch_bounds__(256) void conv_silu_kernel(
    const float* __restrict__ xz,
    const float* __restrict__ cw_fw, const float* __restrict__ cb_fw,
    const float* __restrict__ cw_bw, const float* __restrict__ cb_bw,
    float* __restrict__ xc, __hip_bfloat16* __restrict__ xch)
{
  int dir = blockIdx.y;
  int gid = blockIdx.x * 256 + threadIdx.x;  // over 8192*512
  int d = gid & 511;
  int row = gid >> 9;          // b*4096 + p
  int b = row >> 12, p = row & 4095;
  const float* cw = dir ? cw_bw : cw_fw;
  const float* cb = dir ? cb_bw : cb_fw;
  const float* xi = xz + (size_t)dir * 8192 * 1024;
  float acc = cb[d];
  #pragma unroll
  for (int j = 0; j < 4; j++) {
    int pp = dir ? (p + 3 - j) : (p - 3 + j);
    if (pp >= 0 && pp < 4096)
      acc = fmaf(cw[d * 4 + j], xi[((size_t)(b * 4096 + pp)) * 1024 + d], acc);
  }
  float s = acc / (1.f + __expf(-acc));
  size_t o = ((size_t)dir * 8192 + row) * 512 + d;
  xc[o] = s;
  xch[o] = __float2bfloat16(s);
}

// ---------------- Chunked selective scan, h-per-thread ----------------
__global__ __launch_bounds__(256) void scan_part1(
    const float* __restrict__ xc, const float* __restrict__ dbl,
    const float* __restrict__ dtb,
    const float* __restrict__ Alog_fw, const float* __restrict__ Alog_bw,
    float* __restrict__ Ac, float* __restrict__ Bc)
{
  int tid = threadIdx.x;
  int d = blockIdx.x * 256 + tid;
  int c = blockIdx.y, bd = blockIdx.z, dir = bd >> 1;
  const float* Alog = dir ? Alog_bw : Alog_fw;

  float a[16], h[16];
  #pragma unroll
  for (int n = 0; n < 16; n++) { a[n] = -__expf(Alog[d * 16 + n]); h[n] = 0.f; }

  int base = bd * 4096;
  int stepw = dir ? -1 : 1;
  int t0 = c * CLEN;
  int r = base + (dir ? 4095 - t0 : t0);

  float dtv = dtb[(size_t)r * 512 + d];
  float uv  = xc[(size_t)r * 512 + d];
  float Bn[16];
  {
    const float* br = dbl + (size_t)r * 48 + 16;
    #pragma unroll
    for (int n = 0; n < 16; n++) Bn[n] = br[n];
  }
  float sdt = 0.f;

  for (int i = 0; i < CLEN; i++) {
    float dt_c = dtv, u_c = uv;
    float Bl[16];
    #pragma unroll
    for (int n = 0; n < 16; n++) Bl[n] = Bn[n];
    if (i < CLEN - 1) {
      r += stepw;
      dtv = dtb[(size_t)r * 512 + d];
      uv  = xc[(size_t)r * 512 + d];
      const float* br = dbl + (size_t)r * 48 + 16;
      #pragma unroll
      for (int n = 0; n < 16; n++) Bn[n] = br[n];
    }
    sdt += dt_c;
    float dtu = dt_c * u_c;
    #pragma unroll
    for (int n = 0; n < 16; n++) {
      float g = __expf(dt_c * a[n]);
      h[n] = fmaf(g, h[n], dtu * Bl[n]);
    }
  }
  size_t ob = (((size_t)bd * NCHUNK + c) * 512 + d) * 16;
  #pragma unroll
  for (int n = 0; n < 16; n++) {
    Ac[ob + n] = __expf(a[n] * sdt);
    Bc[ob + n] = h[n];
  }
}

__global__ __launch_bounds__(256) void scan_mid(
    const float* __restrict__ Ac, const float* __restrict__ Bc,
    float* __restrict__ Hin)
{
  int gid = blockIdx.x * 256 + threadIdx.x;   // 0..32767
  int bd = gid >> 13, pos = gid & 8191;
  float h = 0.f;
  for (int c = 0; c < NCHUNK; c++) {
    size_t idx = ((size_t)bd * NCHUNK + c) * 8192 + pos;
    Hin[idx] = h;
    h = Ac[idx] * h + Bc[idx];
  }
}

__global__ __launch_bounds__(256) void scan_part2(
    const float* __restrict__ xz, const float* __restrict__ xc,
    const float* __restrict__ dbl, const float* __restrict__ dtb,
    const float* __restrict__ Alog_fw, const float* __restrict__ Alog_bw,
    const float* __restrict__ Dp_fw, const float* __restrict__ Dp_bw,
    const float* __restrict__ Hin, __hip_bfloat16* __restrict__ yvh)
{
  int tid = threadIdx.x;
  int d = blockIdx.x * 256 + tid;
  int c = blockIdx.y, bd = blockIdx.z, dir = bd >> 1;
  const float* Alog = dir ? Alog_bw : Alog_fw;
  const float* Dp   = dir ? Dp_bw : Dp_fw;
  float Dd = Dp[d];

  float a[16], h[16];
  size_t ob = (((size_t)bd * NCHUNK + c) * 512 + d) * 16;
  #pragma unroll
  for (int n = 0; n < 16; n++) {
    a[n] = -__expf(Alog[d * 16 + n]);
    h[n] = Hin[ob + n];
  }

  int base = bd * 4096;
  int stepw = dir ? -1 : 1;
  int t0 = c * CLEN;
  int r = base + (dir ? 4095 - t0 : t0);

  float dtv = dtb[(size_t)r * 512 + d];
  float uv  = xc[(size_t)r * 512 + d];
  float zv  = xz[(size_t)r * 1024 + 512 + d];
  float Bn[16], Cn[16];
  {
    const float* br = dbl + (size_t)r * 48 + 16;
    #pragma unroll
    for (int n = 0; n < 16; n++) { Bn[n] = br[n]; Cn[n] = br[16 + n]; }
  }

  for (int i = 0; i < CLEN; i++) {
    float dt_c = dtv, u_c = uv, z_c = zv;
    int rc = r;
    float Bl[16], Cl[16];
    #pragma unroll
    for (int n = 0; n < 16; n++) { Bl[n] = Bn[n]; Cl[n] = Cn[n]; }
    if (i < CLEN - 1) {
      r += stepw;
      dtv = dtb[(size_t)r * 512 + d];
      uv  = xc[(size_t)r * 512 + d];
      zv  = xz[(size_t)r * 1024 + 512 + d];
      const float* br = dbl + (size_t)r * 48 + 16;
      #pragma unroll
      for (int n = 0; n < 16; n++) { Bn[n] = br[n]; Cn[n] = br[16 + n]; }
    }
    float dtu = dt_c * u_c;
    float y = 0.f;
    #pragma unroll
    for (int n = 0; n < 16; n++) {
      float g = __expf(dt_c * a[n]);
      h[n] = fmaf(g, h[n], dtu * Bl[n]);
      y = fmaf(h[n], Cl[n], y);
    }
    float sz = z_c / (1.f + __expf(-z_c));
    yvh[(size_t)rc * 512 + d] = __float2bfloat16((y + Dd * u_c) * sz);
  }
}

extern "C" void kernel_launch(void* const* d_in, const int* in_sizes, int n_in,
                              void* d_out, int out_size, void* d_ws, size_t ws_size,
                              hipStream_t stream)
{
  const float* x = (const float*)d_in[0];
  const float* nw[2]     = {(const float*)d_in[1],  (const float*)d_in[11]};
  const float* inp[2]    = {(const float*)d_in[2],  (const float*)d_in[12]};
  const float* cw[2]     = {(const float*)d_in[3],  (const float*)d_in[13]};
  const float* cb[2]     = {(const float*)d_in[4],  (const float*)d_in[14]};
  const float* xp[2]     = {(const float*)d_in[5],  (const float*)d_in[15]};
  const float* dtw[2]    = {(const float*)d_in[6],  (const float*)d_in[16]};
  const float* dtbias[2] = {(const float*)d_in[7],  (const float*)d_in[17]};
  const float* alog[2]   = {(const float*)d_in[8],  (const float*)d_in[18]};
  const float* dvec[2]   = {(const float*)d_in[9],  (const float*)d_in[19]};
  const float* outp[2]   = {(const float*)d_in[10], (const float*)d_in[20]};

  float* ws = (float*)d_ws;
  size_t F = 0;
  float* xz  = ws + F;  F += (size_t)2 * 8192 * 1024;   // f32
  float* xc  = ws + F;  F += (size_t)2 * 8192 * 512;    // f32
  __hip_bfloat16* xch = (__hip_bfloat16*)(ws + F);      // bf16 2*8192*512
  float* xch_f = ws + F;  F += (size_t)2 * 8192 * 256;  // (half the floats)
  float* dbl = ws + F;  F += (size_t)2 * 8192 * 48;
  float* dtb = ws + F;  F += (size_t)2 * 8192 * 512;
  __hip_bfloat16* yvh = (__hip_bfloat16*)(ws + F);      // bf16 2*8192*512
  F += (size_t)2 * 8192 * 256;
  __hip_bfloat16* xnh = (__hip_bfloat16*)(ws + F);      // bf16 2*8192*256
  F += (size_t)2 * 8192 * 128;
  __hip_bfloat16* wb  = (__hip_bfloat16*)(ws + F);      // bf16 835584
  F += 835584 / 2;
  // Ac/Bc (2 x 2,097,152 f32) alias the xch region: xch is dead once the
  // x_proj GEMMs complete, which is strictly before scan_part1.
  float* Ac  = xch_f;
  float* Bc  = Ac + (size_t)4 * NCHUNK * 8192;
  float* Hin = (float*)d_out;   // dead until out_proj fully rewrites d_out
  float* out = (float*)d_out;

  // bf16 weight offsets in wb
  __hip_bfloat16* w_in[2]  = {wb,            wb + 262144};
  __hip_bfloat16* w_out[2] = {wb + 524288,   wb + 655360};
  __hip_bfloat16* w_xp[2]  = {wb + 786432,   wb + 811008};

  cast_weights<<<dim3(3264), 256, 0, stream>>>(
      inp[0], inp[1], outp[0], outp[1], xp[0], xp[1], wb);

  rmsnorm_kernel<<<dim3(8192, 2), 256, 0, stream>>>(x, nw[0], nw[1], xnh);

  for (int dir = 0; dir < 2; dir++) {
    // in_proj: (8192x256)bf16 @ (1024x256)^T bf16 -> f32 (8192x1024)
    gemm_mfma<<<dim3(64, 8), 256, 0, stream>>>(
        xnh + (size_t)dir * 8192 * 256, 256,
        w_in[dir], 256,
        xz + (size_t)dir * 8192 * 1024, 1024,
        8192, 1024, 256, 0, nullptr, 0);
  }

  conv_silu_kernel<<<dim3(16384, 2), 256, 0, stream>>>(
      xz, cw[0], cb[0], cw[1], cb[1], xc, xch);

  for (int dir = 0; dir < 2; dir++) {
    // x_proj: (8192x512)bf16 @ (48x512)^T bf16 -> f32 (8192x48)
    gemm_mfma<<<dim3(64, 1), 256, 0, stream>>>(
        xch + (size_t)dir * 8192 * 512, 512,
        w_xp[dir], 512,
        dbl + (size_t)dir * 8192 * 48, 48,
        8192, 48, 512, 0, nullptr, 0);
    // dt: (8192x16[lda48]) @ (512x16)^T f32 -> softplus(+bias) -> (8192x512)
    gemm_bt<<<dim3(128, 8), 256, 0, stream>>>(
        dbl + (size_t)dir * 8192 * 48, 48,
        dtw[dir], 16,
        dtb + (size_t)dir * 8192 * 512, 512,
        8192, 512, 16, 1, dtbias[dir], nullptr, 0);
  }

  scan_part1<<<dim3(2, NCHUNK, 4), 256, 0, stream>>>(
      xc, dbl, dtb, alog[0], alog[1], Ac, Bc);
  scan_mid<<<dim3(128), 256, 0, stream>>>(Ac, Bc, Hin);
  scan_part2<<<dim3(2, NCHUNK, 4), 256, 0, stream>>>(
      xz, xc, dbl, dtb, alog[0], alog[1], dvec[0], dvec[1], Hin, yvh);

  for (int dir = 0; dir < 2; dir++) {
    // out_proj: (8192x512)bf16 @ (256x512)^T bf16 + x -> out[..., dir*256:+256]
    gemm_mfma<<<dim3(64, 2), 256, 0, stream>>>(
        yvh + (size_t)dir * 8192 * 512, 512,
        w_out[dir], 512,
        out + dir * 256, 512,
        8192, 256, 512, 2, x, 256);
  }
}

// Round 7
// 289.544 us; speedup vs baseline: 6.2124x; 1.0374x over previous
//
#include <hip/hip_runtime.h>
#include <hip/hip_bf16.h>
#include <math.h>

#define NCHUNK 128
#define CLEN 32   // NCHUNK * CLEN == 4096

typedef __attribute__((ext_vector_type(8))) short short8;
typedef __attribute__((ext_vector_type(4))) float f32x4;

__device__ __forceinline__ void gload16(const void* g, void* l) {
  __builtin_amdgcn_global_load_lds(
      (const __attribute__((address_space(1))) void*)g,
      (__attribute__((address_space(3))) void*)l, 16, 0, 0);
}

// ---------------- weight cast: 6 fp32 tensors -> one contiguous bf16 buffer --
__global__ __launch_bounds__(256) void cast_weights(
    const float* __restrict__ a0, const float* __restrict__ a1,
    const float* __restrict__ a2, const float* __restrict__ a3,
    const float* __restrict__ a4, const float* __restrict__ a5,
    __hip_bfloat16* __restrict__ dst)
{
  int gid = blockIdx.x * 256 + threadIdx.x;
  if (gid >= 835584) return;
  int off = gid; const float* s;
  if (off < 262144) s = a0;
  else if ((off -= 262144) < 262144) s = a1;
  else if ((off -= 262144) < 131072) s = a2;
  else if ((off -= 131072) < 131072) s = a3;
  else if ((off -= 131072) < 24576) s = a4;
  else { off -= 24576; s = a5; }
  dst[gid] = __float2bfloat16(s[off]);
}

// ---------------- RMSNorm (bf16 output) ----------------
__global__ __launch_bounds__(256) void rmsnorm_kernel(
    const float* __restrict__ x,
    const float* __restrict__ w_fw, const float* __restrict__ w_bw,
    __hip_bfloat16* __restrict__ xnh)
{
  int row = blockIdx.x;          // b*4096 + l
  int dir = blockIdx.y;
  int tid = threadIdx.x;
  const float* w = dir ? w_bw : w_fw;
  float v = x[row * 256 + tid];
  float ss = v * v;
  #pragma unroll
  for (int m = 32; m; m >>= 1) ss += __shfl_xor(ss, m, 64);
  __shared__ float red[4];
  if ((tid & 63) == 0) red[tid >> 6] = ss;
  __syncthreads();
  float tot = red[0] + red[1] + red[2] + red[3];
  float sc = rsqrtf(tot / 256.f + 1e-5f);
  xnh[((size_t)dir * 8192 + row) * 256 + tid] = __float2bfloat16(v * sc * w[tid]);
}

// ---------------- bf16 MFMA GEMM: C[M,N] = A[M,K] * B[N,K]^T ----------------
__global__ __launch_bounds__(256) void gemm_mfma(
    const __hip_bfloat16* __restrict__ A, int lda,
    const __hip_bfloat16* __restrict__ B, int ldb,
    float* __restrict__ C, int ldc,
    int M, int N, int K,
    int epi, const float* __restrict__ ep_mat, int ep_ld)
{
  __shared__ __align__(16) __hip_bfloat16 As[128 * 32];
  __shared__ __align__(16) __hip_bfloat16 Bs[128 * 32];
  int tid = threadIdx.x;
  int lane = tid & 63, wid = tid >> 6;
  int m0 = blockIdx.x * 128, n0 = blockIdx.y * 128;
  int wr = wid & 1, wc = wid >> 1;

  f32x4 acc[4][4] = {};

  int lrow = lane >> 2;
  int lk8  = (lane & 3) * 8;

  for (int k0 = 0; k0 < K; k0 += 32) {
    __syncthreads();
    #pragma unroll
    for (int s = 0; s < 2; s++) {
      int r = wid * 2 + s;
      int arow = m0 + r * 16 + lrow;
      gload16(A + (size_t)arow * lda + k0 + lk8, &As[r * 512]);
      int brow = n0 + r * 16 + lrow;
      if (brow > N - 1) brow = N - 1;
      gload16(B + (size_t)brow * ldb + k0 + lk8, &Bs[r * 512]);
    }
    __syncthreads();

    short8 af[4], bfr[4];
    #pragma unroll
    for (int i = 0; i < 4; i++)
      af[i] = *(const short8*)&As[(wr * 64 + i * 16 + (lane & 15)) * 32 + (lane >> 4) * 8];
    #pragma unroll
    for (int j = 0; j < 4; j++)
      bfr[j] = *(const short8*)&Bs[(wc * 64 + j * 16 + (lane & 15)) * 32 + (lane >> 4) * 8];
    #pragma unroll
    for (int i = 0; i < 4; i++)
      #pragma unroll
      for (int j = 0; j < 4; j++)
        acc[i][j] = __builtin_amdgcn_mfma_f32_16x16x32_bf16(af[i], bfr[j], acc[i][j], 0, 0, 0);
  }

  int crow = (lane >> 4) * 4;
  int ccol = lane & 15;
  #pragma unroll
  for (int i = 0; i < 4; i++) {
    #pragma unroll
    for (int j = 0; j < 4; j++) {
      int nn = n0 + wc * 64 + j * 16 + ccol;
      if (nn < N) {
        #pragma unroll
        for (int q = 0; q < 4; q++) {
          int mm = m0 + wr * 64 + i * 16 + crow + q;
          float v = acc[i][j][q];
          if (epi == 2) v += ep_mat[(size_t)mm * ep_ld + nn];
          C[(size_t)mm * ldc + nn] = v;
        }
      }
    }
  }
}

// ---------------- fp32 GEMM (kept for dt: K=16) ----------------
__global__ __launch_bounds__(256) void gemm_bt(
    const float* __restrict__ A, int lda,
    const float* __restrict__ B, int ldb,
    float* __restrict__ C, int ldc,
    int M, int N, int K,
    int epi, const float* __restrict__ ep_vec,
    const float* __restrict__ ep_mat, int ep_ld)
{
  __shared__ float As[16][64];
  __shared__ float Bs[16][64];
  int tid = threadIdx.x;
  int tx = tid & 15, ty = tid >> 4;
  int m0 = blockIdx.x * 64, n0 = blockIdx.y * 64;
  int lr = tid >> 2;
  int lk = (tid & 3) << 2;
  float acc[4][4] = {};

  for (int k0 = 0; k0 < K; k0 += 16) {
    float4 av = *(const float4*)&A[(size_t)(m0 + lr) * lda + k0 + lk];
    float4 bv = make_float4(0.f, 0.f, 0.f, 0.f);
    if (n0 + lr < N) bv = *(const float4*)&B[(size_t)(n0 + lr) * ldb + k0 + lk];
    __syncthreads();
    As[lk + 0][lr] = av.x; As[lk + 1][lr] = av.y;
    As[lk + 2][lr] = av.z; As[lk + 3][lr] = av.w;
    Bs[lk + 0][lr] = bv.x; Bs[lk + 1][lr] = bv.y;
    Bs[lk + 2][lr] = bv.z; Bs[lk + 3][lr] = bv.w;
    __syncthreads();
    #pragma unroll
    for (int kk = 0; kk < 16; kk++) {
      float4 a4 = *(const float4*)&As[kk][ty << 2];
      float4 b4 = *(const float4*)&Bs[kk][tx << 2];
      float ar[4] = {a4.x, a4.y, a4.z, a4.w};
      float br[4] = {b4.x, b4.y, b4.z, b4.w};
      #pragma unroll
      for (int i = 0; i < 4; i++)
        #pragma unroll
        for (int j = 0; j < 4; j++)
          acc[i][j] = fmaf(ar[i], br[j], acc[i][j]);
    }
  }

  #pragma unroll
  for (int i = 0; i < 4; i++) {
    int m = m0 + (ty << 2) + i;
    #pragma unroll
    for (int j = 0; j < 4; j++) {
      int n = n0 + (tx << 2) + j;
      if (n < N) {
        float v = acc[i][j];
        if (epi == 1) {
          v += ep_vec[n];
          v = fmaxf(v, 0.f) + log1pf(__expf(-fabsf(v)));
        } else if (epi == 2) {
          v += ep_mat[(size_t)m * ep_ld + n];
        }
        C[(size_t)m * ldc + n] = v;
      }
    }
  }
}

// ---------------- Depthwise causal conv(4) + SiLU (bf16 output) ------
__global__ __launch_bounds__(256) void conv_silu_kernel(
    const float* __restrict__ xz,
    const float* __restrict__ cw_fw, const float* __restrict__ cb_fw,
    const float* __restrict__ cw_bw, const float* __restrict__ cb_bw,
    __hip_bfloat16* __restrict__ xch)
{
  int dir = blockIdx.y;
  int gid = blockIdx.x * 256 + threadIdx.x;  // over 8192*512
  int d = gid & 511;
  int row = gid >> 9;          // b*4096 + p
  int b = row >> 12, p = row & 4095;
  const float* cw = dir ? cw_bw : cw_fw;
  const float* cb = dir ? cb_bw : cb_fw;
  const float* xi = xz + (size_t)dir * 8192 * 1024;
  float acc = cb[d];
  #pragma unroll
  for (int j = 0; j < 4; j++) {
    int pp = dir ? (p + 3 - j) : (p - 3 + j);
    if (pp >= 0 && pp < 4096)
      acc = fmaf(cw[d * 4 + j], xi[((size_t)(b * 4096 + pp)) * 1024 + d], acc);
  }
  float s = acc / (1.f + __expf(-acc));
  xch[((size_t)dir * 8192 + row) * 512 + d] = __float2bfloat16(s);
}

// ---------------- Chunked selective scan, h-per-thread ----------------
__global__ __launch_bounds__(256) void scan_part1(
    const __hip_bfloat16* __restrict__ xch, const float* __restrict__ dbl,
    const float* __restrict__ dtb,
    const float* __restrict__ Alog_fw, const float* __restrict__ Alog_bw,
    float* __restrict__ Ac, float* __restrict__ Bc)
{
  int tid = threadIdx.x;
  int d = blockIdx.x * 256 + tid;
  int c = blockIdx.y, bd = blockIdx.z, dir = bd >> 1;
  const float* Alog = dir ? Alog_bw : Alog_fw;

  float a[16], h[16];
  #pragma unroll
  for (int n = 0; n < 16; n++) { a[n] = -__expf(Alog[d * 16 + n]); h[n] = 0.f; }

  int base = bd * 4096;
  int stepw = dir ? -1 : 1;
  int t0 = c * CLEN;
  int r = base + (dir ? 4095 - t0 : t0);

  float dtv = dtb[(size_t)r * 512 + d];
  float uv  = __bfloat162float(xch[(size_t)r * 512 + d]);
  float Bn[16];
  {
    const float* br = dbl + (size_t)r * 48 + 16;
    #pragma unroll
    for (int n = 0; n < 16; n++) Bn[n] = br[n];
  }
  float sdt = 0.f;

  for (int i = 0; i < CLEN; i++) {
    float dt_c = dtv, u_c = uv;
    float Bl[16];
    #pragma unroll
    for (int n = 0; n < 16; n++) Bl[n] = Bn[n];
    if (i < CLEN - 1) {
      r += stepw;
      dtv = dtb[(size_t)r * 512 + d];
      uv  = __bfloat162float(xch[(size_t)r * 512 + d]);
      const float* br = dbl + (size_t)r * 48 + 16;
      #pragma unroll
      for (int n = 0; n < 16; n++) Bn[n] = br[n];
    }
    sdt += dt_c;
    float dtu = dt_c * u_c;
    #pragma unroll
    for (int n = 0; n < 16; n++) {
      float g = __expf(dt_c * a[n]);
      h[n] = fmaf(g, h[n], dtu * Bl[n]);
    }
  }
  size_t ob = (((size_t)bd * NCHUNK + c) * 512 + d) * 16;
  #pragma unroll
  for (int n = 0; n < 16; n++) {
    Ac[ob + n] = __expf(a[n] * sdt);
    Bc[ob + n] = h[n];
  }
}

__global__ __launch_bounds__(256) void scan_mid(
    const float* __restrict__ Ac, const float* __restrict__ Bc,
    float* __restrict__ Hin)
{
  int gid = blockIdx.x * 256 + threadIdx.x;   // 0..32767
  int bd = gid >> 13, pos = gid & 8191;
  float h = 0.f;
  for (int c = 0; c < NCHUNK; c++) {
    size_t idx = ((size_t)bd * NCHUNK + c) * 8192 + pos;
    Hin[idx] = h;
    h = Ac[idx] * h + Bc[idx];
  }
}

__global__ __launch_bounds__(256) void scan_part2(
    const float* __restrict__ xz, const __hip_bfloat16* __restrict__ xch,
    const float* __restrict__ dbl, const float* __restrict__ dtb,
    const float* __restrict__ Alog_fw, const float* __restrict__ Alog_bw,
    const float* __restrict__ Dp_fw, const float* __restrict__ Dp_bw,
    const float* __restrict__ Hin, __hip_bfloat16* __restrict__ yvh)
{
  int tid = threadIdx.x;
  int d = blockIdx.x * 256 + tid;
  int c = blockIdx.y, bd = blockIdx.z, dir = bd >> 1;
  const float* Alog = dir ? Alog_bw : Alog_fw;
  const float* Dp   = dir ? Dp_bw : Dp_fw;
  float Dd = Dp[d];

  float a[16], h[16];
  size_t ob = (((size_t)bd * NCHUNK + c) * 512 + d) * 16;
  #pragma unroll
  for (int n = 0; n < 16; n++) {
    a[n] = -__expf(Alog[d * 16 + n]);
    h[n] = Hin[ob + n];
  }

  int base = bd * 4096;
  int stepw = dir ? -1 : 1;
  int t0 = c * CLEN;
  int r = base + (dir ? 4095 - t0 : t0);

  float dtv = dtb[(size_t)r * 512 + d];
  float uv  = __bfloat162float(xch[(size_t)r * 512 + d]);
  float zv  = xz[(size_t)r * 1024 + 512 + d];
  float Bn[16], Cn[16];
  {
    const float* br = dbl + (size_t)r * 48 + 16;
    #pragma unroll
    for (int n = 0; n < 16; n++) { Bn[n] = br[n]; Cn[n] = br[16 + n]; }
  }

  for (int i = 0; i < CLEN; i++) {
    float dt_c = dtv, u_c = uv, z_c = zv;
    int rc = r;
    float Bl[16], Cl[16];
    #pragma unroll
    for (int n = 0; n < 16; n++) { Bl[n] = Bn[n]; Cl[n] = Cn[n]; }
    if (i < CLEN - 1) {
      r += stepw;
      dtv = dtb[(size_t)r * 512 + d];
      uv  = __bfloat162float(xch[(size_t)r * 512 + d]);
      zv  = xz[(size_t)r * 1024 + 512 + d];
      const float* br = dbl + (size_t)r * 48 + 16;
      #pragma unroll
      for (int n = 0; n < 16; n++) { Bn[n] = br[n]; Cn[n] = br[16 + n]; }
    }
    float dtu = dt_c * u_c;
    float y = 0.f;
    #pragma unroll
    for (int n = 0; n < 16; n++) {
      float g = __expf(dt_c * a[n]);
      h[n] = fmaf(g, h[n], dtu * Bl[n]);
      y = fmaf(h[n], Cl[n], y);
    }
    float sz = z_c / (1.f + __expf(-z_c));
    yvh[(size_t)rc * 512 + d] = __float2bfloat16((y + Dd * u_c) * sz);
  }
}

extern "C" void kernel_launch(void* const* d_in, const int* in_sizes, int n_in,
                              void* d_out, int out_size, void* d_ws, size_t ws_size,
                              hipStream_t stream)
{
  const float* x = (const float*)d_in[0];
  const float* nw[2]     = {(const float*)d_in[1],  (const float*)d_in[11]};
  const float* inp[2]    = {(const float*)d_in[2],  (const float*)d_in[12]};
  const float* cw[2]     = {(const float*)d_in[3],  (const float*)d_in[13]};
  const float* cb[2]     = {(const float*)d_in[4],  (const float*)d_in[14]};
  const float* xp[2]     = {(const float*)d_in[5],  (const float*)d_in[15]};
  const float* dtw[2]    = {(const float*)d_in[6],  (const float*)d_in[16]};
  const float* dtbias[2] = {(const float*)d_in[7],  (const float*)d_in[17]};
  const float* alog[2]   = {(const float*)d_in[8],  (const float*)d_in[18]};
  const float* dvec[2]   = {(const float*)d_in[9],  (const float*)d_in[19]};
  const float* outp[2]   = {(const float*)d_in[10], (const float*)d_in[20]};

  float* ws = (float*)d_ws;
  size_t F = 0;
  float* xz  = ws + F;  F += (size_t)2 * 8192 * 1024;   // f32 16.78M
  __hip_bfloat16* xch = (__hip_bfloat16*)(ws + F);      // bf16 2*8192*512
  F += (size_t)2 * 8192 * 256;
  float* dbl = ws + F;  F += (size_t)2 * 8192 * 48;
  float* dtb = ws + F;  F += (size_t)2 * 8192 * 512;
  __hip_bfloat16* yvh = (__hip_bfloat16*)(ws + F);      // bf16 2*8192*512
  F += (size_t)2 * 8192 * 256;
  __hip_bfloat16* xnh = (__hip_bfloat16*)(ws + F);      // bf16 2*8192*256
  F += (size_t)2 * 8192 * 128;
  __hip_bfloat16* wb  = (__hip_bfloat16*)(ws + F);      // bf16 835584
  F += 835584 / 2;
  float* Ac  = ws + F;  F += (size_t)4 * NCHUNK * 8192; // f32 4.19M
  float* Bc  = ws + F;  F += (size_t)4 * NCHUNK * 8192; // f32 4.19M
  float* Hin = (float*)d_out;   // 4*NCHUNK*8192 = 4.19M floats = d_out exactly
  float* out = (float*)d_out;

  __hip_bfloat16* w_in[2]  = {wb,            wb + 262144};
  __hip_bfloat16* w_out[2] = {wb + 524288,   wb + 655360};
  __hip_bfloat16* w_xp[2]  = {wb + 786432,   wb + 811008};

  cast_weights<<<dim3(3264), 256, 0, stream>>>(
      inp[0], inp[1], outp[0], outp[1], xp[0], xp[1], wb);

  rmsnorm_kernel<<<dim3(8192, 2), 256, 0, stream>>>(x, nw[0], nw[1], xnh);

  for (int dir = 0; dir < 2; dir++) {
    // in_proj: (8192x256)bf16 @ (1024x256)^T bf16 -> f32 (8192x1024)
    gemm_mfma<<<dim3(64, 8), 256, 0, stream>>>(
        xnh + (size_t)dir * 8192 * 256, 256,
        w_in[dir], 256,
        xz + (size_t)dir * 8192 * 1024, 1024,
        8192, 1024, 256, 0, nullptr, 0);
  }

  conv_silu_kernel<<<dim3(16384, 2), 256, 0, stream>>>(
      xz, cw[0], cb[0], cw[1], cb[1], xch);

  for (int dir = 0; dir < 2; dir++) {
    // x_proj: (8192x512)bf16 @ (48x512)^T bf16 -> f32 (8192x48)
    gemm_mfma<<<dim3(64, 1), 256, 0, stream>>>(
        xch + (size_t)dir * 8192 * 512, 512,
        w_xp[dir], 512,
        dbl + (size_t)dir * 8192 * 48, 48,
        8192, 48, 512, 0, nullptr, 0);
    // dt: (8192x16[lda48]) @ (512x16)^T f32 -> softplus(+bias) -> (8192x512)
    gemm_bt<<<dim3(128, 8), 256, 0, stream>>>(
        dbl + (size_t)dir * 8192 * 48, 48,
        dtw[dir], 16,
        dtb + (size_t)dir * 8192 * 512, 512,
        8192, 512, 16, 1, dtbias[dir], nullptr, 0);
  }

  scan_part1<<<dim3(2, NCHUNK, 4), 256, 0, stream>>>(
      xch, dbl, dtb, alog[0], alog[1], Ac, Bc);
  scan_mid<<<dim3(128), 256, 0, stream>>>(Ac, Bc, Hin);
  scan_part2<<<dim3(2, NCHUNK, 4), 256, 0, stream>>>(
      xz, xch, dbl, dtb, alog[0], alog[1], dvec[0], dvec[1], Hin, yvh);

  for (int dir = 0; dir < 2; dir++) {
    // out_proj: (8192x512)bf16 @ (256x512)^T bf16 + x -> out[..., dir*256:+256]
    gemm_mfma<<<dim3(64, 2), 256, 0, stream>>>(
        yvh + (size_t)dir * 8192 * 512, 512,
        w_out[dir], 512,
        out + dir * 256, 512,
        8192, 256, 512, 2, x, 256);
  }
}